// Round 6
// baseline (188.755 us; speedup 1.0000x reference)
//
#include <hip/hip_runtime.h>
#include <stdint.h>

// MultiScaleRetention pipeline, R6.
// vs R5: (1) gemm_qkv epilogue decay via per-thread gamma-multiplication chains
// (1 log2f + 1 exp2f per thread instead of 64 libm exp2f); (2) gemm_qkv
// single-pass 128x128 epilogue transpose in 32KB LDS (was 2 half-wave passes,
// 4 extra barriers); (3) retention j-chunk 128 (half the barriers, 64 MFMA per
// barrier pair, LDS 64KB = 2 blocks/CU which matches the 2-blocks/CU grid).
//
// ws layout: [0,8) xb (reused as Y1 fp32 [bh][64d][1024t] after gemm_qkv)
// [8,10) wqb [10,12) wkb [12,14) wvb [14,16) wob
// [16,24) qb [B,H,T,DH] bf16  [24,32) kb same  [32,40) vtb [B,H,DH,T] bf16
// [40,56) Y0 fp32 [bh][64d][2048t]  [56,64) ynb bf16 [t][c]
// [64MB) st (128 floats)

#define SEQ 2048

typedef __bf16 bf16x8 __attribute__((ext_vector_type(8)));
typedef float  floatx4 __attribute__((ext_vector_type(4)));
typedef unsigned short ushort4v __attribute__((ext_vector_type(4)));

__device__ __forceinline__ unsigned short f2bf(float f){
    __bf16 h = (__bf16)f;
    return __builtin_bit_cast(unsigned short, h);
}

__device__ __forceinline__ void gload_lds16(const void* g, void* l){
    __builtin_amdgcn_global_load_lds(
        (const __attribute__((address_space(1))) unsigned int*)g,
        (__attribute__((address_space(3))) unsigned int*)l, 16, 0, 0);
}

// ---------------------------------------------------------------- fused cvt + st zero
__global__ __launch_bounds__(256)
void cvt_all(const float* __restrict__ x,
             const float* __restrict__ w0, const float* __restrict__ w1,
             const float* __restrict__ w2, const float* __restrict__ w3,
             unsigned short* __restrict__ xb,
             unsigned short* __restrict__ o0, unsigned short* __restrict__ o1,
             unsigned short* __restrict__ o2, unsigned short* __restrict__ o3,
             float* __restrict__ st){
    const int blk = blockIdx.x;
    if(blk == 0 && threadIdx.x < 128) st[threadIdx.x] = 0.0f;
    const float* src; unsigned short* dst; size_t i;
    if(blk < 4096){ src = x; dst = xb; i = (size_t)blk*256 + threadIdx.x; }
    else {
        const int seg = (blk - 4096) >> 10;
        src = seg==0?w0:seg==1?w1:seg==2?w2:w3;
        dst = seg==0?o0:seg==1?o1:seg==2?o2:o3;
        i = (size_t)((blk - 4096) & 1023)*256 + threadIdx.x;
    }
    float4 v = ((const float4*)src)[i];
    ushort4v o;
    o[0]=f2bf(v.x); o[1]=f2bf(v.y); o[2]=f2bf(v.z); o[3]=f2bf(v.w);
    *(ushort4v*)&dst[i*4] = o;
}

// ---------------------------------------------------------------- fused QKV GEMM
// grid (32,24): y<8 Q (scale 0.125*gamma^t), y<16 K (gamma^-t), else V^T.
// Epilogue: single-pass 128x128 LDS transpose (32KB), decay via mul chains.
__global__ __launch_bounds__(256, 3)
void gemm_qkv(const unsigned short* __restrict__ A,
              const unsigned short* __restrict__ Wq,
              const unsigned short* __restrict__ Wk,
              const unsigned short* __restrict__ Wv,
              unsigned short* __restrict__ Qo,
              unsigned short* __restrict__ Ko,
              unsigned short* __restrict__ Vo)
{
    __shared__ unsigned short smem[16384];  // main loop: As=[0,4096), Bs=[4096,8192); epi: 128x128
    unsigned short* As = smem;
    unsigned short* Bs = smem + 4096;
    const int tid  = threadIdx.x;
    const int w    = tid >> 6, lane = tid & 63, q = lane >> 4, cl = lane & 15;
    const int i0   = blockIdx.x * 128;
    const int ysel = blockIdx.y;
    int mode, n0;
    const unsigned short* Bw;
    unsigned short* O;
    if(ysel < 8)      { mode = 0; Bw = Wq; O = Qo; n0 = ysel*128; }
    else if(ysel < 16){ mode = 1; Bw = Wk; O = Ko; n0 = (ysel-8)*128; }
    else              { mode = 2; Bw = Wv; O = Vo; n0 = (ysel-16)*128; }
    const int wm = (w & 1) * 64, wn = (w >> 1) * 64;

    floatx4 acc[4][4];
    #pragma unroll
    for(int a=0;a<4;a++)
        #pragma unroll
        for(int b=0;b<4;b++) acc[a][b] = (floatx4)(0.0f);

    const int srow = lane >> 2;
    const int soff = (lane & 3) * 16;

    for(int k0 = 0; k0 < 1024; k0 += 32){
        __syncthreads();
        #pragma unroll
        for(int t=0;t<2;t++){
            const int ra = (w*2 + t) * 16;
            gload_lds16((const char*)A  + ((size_t)(i0 + ra + srow)*1024 + k0)*2 + soff,
                        (char*)&As[ra*32]);
            gload_lds16((const char*)Bw + ((size_t)(n0 + ra + srow)*1024 + k0)*2 + soff,
                        (char*)&Bs[ra*32]);
        }
        __syncthreads();

        bf16x8 af[4], bfr[4];
        #pragma unroll
        for(int mi=0;mi<4;mi++) af[mi]  = *(const bf16x8*)&As[(wm + mi*16 + cl)*32 + q*8];
        #pragma unroll
        for(int ni=0;ni<4;ni++) bfr[ni] = *(const bf16x8*)&Bs[(wn + ni*16 + cl)*32 + q*8];
        #pragma unroll
        for(int mi=0;mi<4;mi++)
            #pragma unroll
            for(int ni=0;ni<4;ni++)
                acc[mi][ni] = __builtin_amdgcn_mfma_f32_16x16x32_bf16(af[mi], bfr[ni], acc[mi][ni], 0, 0, 0);
    }

    const int b = i0 >> 11;
    const int tb = i0 & 2047;               // within-batch token base (no wrap: tiles are 128-aligned)
    __syncthreads();                        // protect smem reuse vs last frag reads

    if(mode < 2){
        // decay chain constants: h constant per thread (wn fixed, ni*16 < 64)
        const int h = (n0 + wn) >> 6;
        const float gamma = 1.0f - __builtin_ldexpf(1.0f, -5 - h);
        const float lgh = log2f(gamma);
        float g1p, base;
        if(mode == 0){ g1p = gamma;        base = exp2f((float)tb * lgh) * 0.125f; }
        else         { g1p = 1.0f / gamma; base = exp2f(-(float)tb * lgh); }
        const float g2 = g1p*g1p, g4 = g2*g2, g8 = g4*g4, g16 = g8*g8;
        const float g32 = g16*g16, g64 = g32*g32;
        float sq = base;
        if(q & 1) sq *= g4;
        if(q & 2) sq *= g8;
        if(wm)    sq *= g64;

        // write [128 t][128 d] swizzled
        #pragma unroll
        for(int ni=0;ni<4;ni++){
            const int d = wn + ni*16 + cl, d8 = d >> 3, d7 = d & 7;
            float cur = sq;
            #pragma unroll
            for(int mi=0;mi<4;mi++){
                const int tr0 = wm + mi*16 + q*4;
                float v0 = cur, v1 = v0*g1p, v2 = v1*g1p, v3 = v2*g1p;
                smem[(tr0+0)*128 + ((d8 ^ ((tr0+0)&7))*8) + d7] = f2bf(acc[mi][ni][0]*v0);
                smem[(tr0+1)*128 + ((d8 ^ ((tr0+1)&7))*8) + d7] = f2bf(acc[mi][ni][1]*v1);
                smem[(tr0+2)*128 + ((d8 ^ ((tr0+2)&7))*8) + d7] = f2bf(acc[mi][ni][2]*v2);
                smem[(tr0+3)*128 + ((d8 ^ ((tr0+3)&7))*8) + d7] = f2bf(acc[mi][ni][3]*v3);
                cur *= g16;
            }
        }
        __syncthreads();
        // read + store: 2 rows/thread, 4-lane 64B runs
        const int part = tid & 3;
        #pragma unroll
        for(int rr=0;rr<2;rr++){
            const int row = (tid>>2)*2 + rr;
            const int tt = tb + row;
            #pragma unroll
            for(int k=0;k<4;k++){
                const int c = k*4 + part;
                bf16x8 vrow = *(const bf16x8*)&smem[row*128 + ((c ^ (row&7))*8)];
                const int h2 = (n0 + c*8) >> 6, dd = (c*8) & 63;
                *(bf16x8*)&O[(((size_t)(b*16 + h2))*2048 + tt)*64 + dd] = vrow;
            }
        }
    } else {
        // V^T: write [128 d][128 t] swizzled (b64 packed), read rows coalesced
        #pragma unroll
        for(int ni=0;ni<4;ni++){
            const int drow = wn + ni*16 + cl, dr7 = drow & 7;
            #pragma unroll
            for(int mi=0;mi<4;mi++){
                const int ch = (wm>>3) + mi*2 + (q>>1);     // t-chunk 0..15
                const int phys = (ch & 8) | ((ch & 7) ^ dr7);
                ushort4v pk;
                #pragma unroll
                for(int r=0;r<4;r++) pk[r] = f2bf(acc[mi][ni][r]);
                *(ushort4v*)&smem[drow*128 + phys*8 + (q&1)*4] = pk;
            }
        }
        __syncthreads();
        const int part = tid & 3;
        #pragma unroll
        for(int rr=0;rr<2;rr++){
            const int row = (tid>>2)*2 + rr;                // d-row 0..127
            const int dg = n0 + row;
            const int h2 = dg >> 6, dd = dg & 63;
            #pragma unroll
            for(int k=0;k<4;k++){
                const int c = k*4 + part;
                const int phys = (c & 8) | ((c & 7) ^ (row & 7));
                bf16x8 vrow = *(const bf16x8*)&smem[row*128 + phys*8];
                *(bf16x8*)&O[(((size_t)(b*16 + h2))*64 + dd)*2048 + tb + c*8] = vrow;
            }
        }
    }
}

// ---------------------------------------------------------------- retention core
// j-chunk 128. S^T = K*Q^T (b64 Ss writes / b128 reads), Y^T = V^T*S^T.
// grid (16,32): pair (x,15-x), s=0 gets 9 chunks (all of bt=x + first 8-x of
// 15-x), s=1 gets last 8 chunks of 15-x (rows >=1024 -> compact Y1).
__global__ __launch_bounds__(256, 2)
void retention(const unsigned short* __restrict__ Q,
               const unsigned short* __restrict__ K,
               const unsigned short* __restrict__ VT,
               float* __restrict__ Y0, float* __restrict__ Y1)
{
    __shared__ unsigned short Ks[128*64];    // j-rows x 64d, 8 chunks/row, XOR-swz
    __shared__ unsigned short Vs[64*128];    // d-rows x 128j, 16 chunks/row, XOR-swz low3
    __shared__ unsigned short Ss[4][32*128]; // per-wave, i-rows x 128j, XOR-swz low3

    const int tid = threadIdx.x;
    const int w = tid >> 6, lane = tid & 63, q = lane >> 4, cl = lane & 15;
    const int s = blockIdx.x >> 3, x = blockIdx.x & 7;
    const int bh = blockIdx.y;
    const int wm = w * 32;
    const int l3 = lane >> 3, l7 = lane & 7;
    const int cl7 = cl & 7;

    int segbt[2], segjb[2], segje[2], nseg;
    if(s == 0){ nseg = 2;
        segbt[0] = x;     segjb[0] = 0;     segje[0] = x + 1;
        segbt[1] = 15-x;  segjb[1] = 0;     segje[1] = 8 - x;
    } else { nseg = 1;
        segbt[0] = 15-x;  segjb[0] = 8-x;   segje[0] = 16 - x;
    }

    for(int seg = 0; seg < nseg; seg++){
        const int bt = segbt[seg], jb = segjb[seg], je = segje[seg];
        const int i0 = bt * 128;

        bf16x8 qf[2][2];
        #pragma unroll
        for(int mi=0;mi<2;mi++)
            #pragma unroll
            for(int kk=0;kk<2;kk++)
                qf[mi][kk] = *(const bf16x8*)(Q + ((size_t)bh*SEQ + i0 + wm + mi*16 + cl)*64 + kk*32 + q*8);

        floatx4 Yacc[2][4];
        #pragma unroll
        for(int a=0;a<2;a++)
            #pragma unroll
            for(int b=0;b<4;b++) Yacc[a][b] = (floatx4)(0.0f);

        for(int jt = jb; jt < je; jt++){
            const int j0 = jt * 128;
            __syncthreads();
            // stage K: 128 rows x 128B, 4 gloads/thread
            #pragma unroll
            for(int t=0;t<4;t++){
                const int r = w*32 + t*8 + l3;
                gload_lds16((const char*)K + (((size_t)bh*SEQ + j0 + r)*64 + (l7^l3)*8)*2,
                            (char*)&Ks[(w*32 + t*8)*64]);
            }
            // stage V^T: 64 rows x 256B, 4 gloads/thread
            #pragma unroll
            for(int t=0;t<4;t++){
                const int r = w*16 + t*4 + (lane>>4);
                const int pc = lane & 15;
                const int cc = (pc & 8) | ((pc & 7) ^ (r & 7));
                gload_lds16((const char*)VT + (((size_t)bh*64 + r)*SEQ + j0 + cc*8)*2,
                            (char*)&Vs[(w*16 + t*4)*128]);
            }
            __syncthreads();

            // S^T[j 128][i 32] = K*Q^T
            floatx4 St[2][8];
            #pragma unroll
            for(int a=0;a<2;a++)
                #pragma unroll
                for(int b=0;b<8;b++) St[a][b] = (floatx4)(0.0f);
            #pragma unroll
            for(int kk=0;kk<2;kk++){
                #pragma unroll
                for(int ni=0;ni<8;ni++){
                    bf16x8 ak = *(const bf16x8*)&Ks[(ni*16 + cl)*64 + ((kk*4+q) ^ cl7)*8];
                    St[0][ni] = __builtin_amdgcn_mfma_f32_16x16x32_bf16(ak, qf[0][kk], St[0][ni], 0,0,0);
                    St[1][ni] = __builtin_amdgcn_mfma_f32_16x16x32_bf16(ak, qf[1][kk], St[1][ni], 0,0,0);
                }
            }

            // mask (diagonal chunk only) + b64 pack into per-wave Ss
            const bool need_mask = (jt == bt);
            unsigned short* SsW = Ss[w];
            #pragma unroll
            for(int mi=0;mi<2;mi++){
                const int row = mi*16 + cl;
                const int sw = row & 7;
                const int ig = i0 + wm + row;
                #pragma unroll
                for(int ni=0;ni<8;ni++){
                    const int jc = ni*2 + (q>>1);
                    const int phys = (jc & 8) | ((jc & 7) ^ sw);
                    ushort4v pk;
                    #pragma unroll
                    for(int r=0;r<4;r++){
                        float v = St[mi][ni][r];
                        if(need_mask){
                            const int jg = j0 + ni*16 + q*4 + r;
                            if(ig < jg) v = 0.0f;
                        }
                        pk[r] = f2bf(v);
                    }
                    *(ushort4v*)&SsW[row*128 + phys*8 + (q&1)*4] = pk;
                }
            }
            asm volatile("s_waitcnt lgkmcnt(0)" ::: "memory");  // per-wave region

            // Y^T += V^T * S^T
            #pragma unroll
            for(int kk=0;kk<4;kk++){
                const int c = kk*4 + q;
                const int phys = (c & 8) | ((c & 7) ^ cl7);
                bf16x8 bs0 = *(const bf16x8*)&SsW[( 0 + cl)*128 + phys*8];
                bf16x8 bs1 = *(const bf16x8*)&SsW[(16 + cl)*128 + phys*8];
                #pragma unroll
                for(int nt=0;nt<4;nt++){
                    bf16x8 av = *(const bf16x8*)&Vs[(nt*16 + cl)*128 + phys*8];
                    Yacc[0][nt] = __builtin_amdgcn_mfma_f32_16x16x32_bf16(av, bs0, Yacc[0][nt], 0,0,0);
                    Yacc[1][nt] = __builtin_amdgcn_mfma_f32_16x16x32_bf16(av, bs1, Yacc[1][nt], 0,0,0);
                }
            }
        }

        // flush Y^T: (d = nt*16+q*4+r, i = i0+wm+mi*16+cl), coalesced in t
        #pragma unroll
        for(int mi=0;mi<2;mi++)
            #pragma unroll
            for(int nt=0;nt<4;nt++){
                const int ig = i0 + wm + mi*16 + cl;
                #pragma unroll
                for(int r=0;r<4;r++){
                    const int d = nt*16 + q*4 + r;
                    if(s == 0)
                        Y0[((size_t)bh*64 + d)*2048 + ig] = Yacc[mi][nt][r];
                    else
                        Y1[((size_t)bh*64 + d)*1024 + ig - 1024] = Yacc[mi][nt][r];
                }
            }
    }
}

// ---------------------------------------------------------------- GroupNorm stats
__global__ __launch_bounds__(256)
void gn_stats(const float* __restrict__ Y0, const float* __restrict__ Y1,
              float* __restrict__ st){
    const int g = blockIdx.x >> 3, s8 = blockIdx.x & 7;
    if(g >= 32) return;
    float s1 = 0.f, s2 = 0.f;
    #pragma unroll
    for(int it=0; it<16; it++){
        const int idx = it*256 + threadIdx.x;
        const int dl = idx >> 9;
        const int t4 = idx & 511;
        const int drow = g*64 + s8*8 + dl;
        float4 v = ((const float4*)Y0)[(size_t)drow*512 + t4];
        if(t4 >= 256){
            float4 u = ((const float4*)Y1)[(size_t)drow*256 + t4 - 256];
            v.x += u.x; v.y += u.y; v.z += u.z; v.w += u.w;
        }
        s1 += v.x + v.y + v.z + v.w;
        s2 += v.x*v.x + v.y*v.y + v.z*v.z + v.w*v.w;
    }
    #pragma unroll
    for(int o=32;o>0;o>>=1){ s1 += __shfl_down(s1,o); s2 += __shfl_down(s2,o); }
    __shared__ float r1[4], r2[4];
    const int w = threadIdx.x >> 6, lane = threadIdx.x & 63;
    if(lane == 0){ r1[w] = s1; r2[w] = s2; }
    __syncthreads();
    if(threadIdx.x == 0){
        atomicAdd(&st[g*2+0], r1[0]+r1[1]+r1[2]+r1[3]);
        atomicAdd(&st[g*2+1], r2[0]+r2[1]+r2[2]+r2[3]);
    }
}

// ---------------------------------------------------------------- GroupNorm apply + transpose
__global__ __launch_bounds__(256)
void gn_norm(const float* __restrict__ Y0, const float* __restrict__ Y1,
             const float* __restrict__ st,
             const float* __restrict__ gw, const float* __restrict__ gb,
             unsigned short* __restrict__ Out){
    __shared__ unsigned short T[64*72];
    const int g = blockIdx.x >> 5;
    if(g >= 32) return;
    const int t0 = (blockIdx.x & 31) * 64;
    const int h = g & 15, b = g >> 4;
    const float mean = st[g*2+0] * (1.0f/131072.0f);
    const float var  = st[g*2+1] * (1.0f/131072.0f) - mean*mean;
    const float inv  = rsqrtf(var + 1e-5f);
    const int tid = threadIdx.x;
    const bool hi = (t0 >= 1024);
    #pragma unroll
    for(int kk=0;kk<4;kk++){
        const int f4 = kk*256 + tid;
        const int d = f4 >> 4;
        const int t4l = f4 & 15;
        float4 v = ((const float4*)Y0)[(size_t)(g*64 + d)*512 + (t0>>2) + t4l];
        if(hi){
            float4 u = ((const float4*)Y1)[(size_t)(g*64 + d)*256 + ((t0-1024)>>2) + t4l];
            v.x += u.x; v.y += u.y; v.z += u.z; v.w += u.w;
        }
        const int c = h*64 + d;
        const float sc = inv * gw[c];
        const float bs = gb[c] - mean*sc;
        const int tl = t4l*4;
        T[(tl+0)*72 + d] = f2bf(v.x*sc + bs);
        T[(tl+1)*72 + d] = f2bf(v.y*sc + bs);
        T[(tl+2)*72 + d] = f2bf(v.z*sc + bs);
        T[(tl+3)*72 + d] = f2bf(v.w*sc + bs);
    }
    __syncthreads();
    #pragma unroll
    for(int it=0; it<2; it++){
        const int idx = it*256 + tid;
        const int tl = idx >> 3, segp = idx & 7;
        bf16x8 vrow = *(const bf16x8*)&T[tl*72 + segp*8];
        *(bf16x8*)&Out[((size_t)(b*2048 + t0 + tl))*1024 + h*64 + segp*8] = vrow;
    }
}

// ---------------------------------------------------------------- output GEMM
__global__ __launch_bounds__(256, 3)
void gemm_out(const unsigned short* __restrict__ A,
              const unsigned short* __restrict__ Bw,
              float* __restrict__ O)
{
    __shared__ unsigned short As[128*32];
    __shared__ unsigned short Bs[64*32];
    const int tid = threadIdx.x;
    const int w = tid >> 6, lane = tid & 63, q = lane >> 4, cl = lane & 15;
    const int i0 = blockIdx.x * 128, n0 = blockIdx.y * 64;
    const int wm = (w & 1) * 64, wn = (w >> 1) * 32;

    floatx4 acc[4][2];
    #pragma unroll
    for(int a=0;a<4;a++)
        #pragma unroll
        for(int b=0;b<2;b++) acc[a][b] = (floatx4)(0.0f);

    const int srow = lane >> 2;
    const int soff = (lane & 3) * 16;

    for(int k0 = 0; k0 < 1024; k0 += 32){
        __syncthreads();
        #pragma unroll
        for(int t=0;t<2;t++){
            const int ra = w*32 + t*16;
            gload_lds16((const char*)A + ((size_t)(i0 + ra + srow)*1024 + k0)*2 + soff,
                        (char*)&As[ra*32]);
        }
        gload_lds16((const char*)Bw + ((size_t)(n0 + w*16 + srow)*1024 + k0)*2 + soff,
                    (char*)&Bs[(w*16)*32]);
        __syncthreads();

        bf16x8 af[4], bfr[2];
        #pragma unroll
        for(int mi=0;mi<4;mi++) af[mi]  = *(const bf16x8*)&As[(wm + mi*16 + cl)*32 + q*8];
        #pragma unroll
        for(int ni=0;ni<2;ni++) bfr[ni] = *(const bf16x8*)&Bs[(wn + ni*16 + cl)*32 + q*8];
        #pragma unroll
        for(int mi=0;mi<4;mi++)
            #pragma unroll
            for(int ni=0;ni<2;ni++)
                acc[mi][ni] = __builtin_amdgcn_mfma_f32_16x16x32_bf16(af[mi], bfr[ni], acc[mi][ni], 0, 0, 0);
    }

    #pragma unroll
    for(int mi=0;mi<4;mi++)
        #pragma unroll
        for(int ni=0;ni<2;ni++){
            const int gi = i0 + wm + mi*16 + q*4;
            const int gn = n0 + wn + ni*16 + cl;
            #pragma unroll
            for(int r=0;r<4;r++) O[(size_t)(gi + r)*1024 + gn] = acc[mi][ni][r];
        }
}

// ---------------------------------------------------------------- launch
extern "C" void kernel_launch(void* const* d_in, const int* in_sizes, int n_in,
                              void* d_out, int out_size, void* d_ws, size_t ws_size,
                              hipStream_t stream){
    const float* x  = (const float*)d_in[0];
    const float* Wq = (const float*)d_in[1];
    const float* Wk = (const float*)d_in[2];
    const float* Wv = (const float*)d_in[3];
    const float* Wo = (const float*)d_in[4];
    const float* gw = (const float*)d_in[5];
    const float* gb = (const float*)d_in[6];

    char* ws = (char*)d_ws;
    unsigned short* xb  = (unsigned short*)(ws + ((size_t) 0<<20));
    unsigned short* wqb = (unsigned short*)(ws + ((size_t) 8<<20));
    unsigned short* wkb = (unsigned short*)(ws + ((size_t)10<<20));
    unsigned short* wvb = (unsigned short*)(ws + ((size_t)12<<20));
    unsigned short* wob = (unsigned short*)(ws + ((size_t)14<<20));
    unsigned short* qb  = (unsigned short*)(ws + ((size_t)16<<20));
    unsigned short* kb  = (unsigned short*)(ws + ((size_t)24<<20));
    unsigned short* vtb = (unsigned short*)(ws + ((size_t)32<<20));
    float*          y0  = (float*)         (ws + ((size_t)40<<20));
    unsigned short* ynb = (unsigned short*)(ws + ((size_t)56<<20));
    float*          y1  = (float*)         (ws + ((size_t) 0<<20));   // over xb
    float*          st  = (float*)         (ws + ((size_t)64<<20));   // 128 floats

    cvt_all<<<8192, 256, 0, stream>>>(x, Wq, Wk, Wv, Wo, xb, wqb, wkb, wvb, wob, st);

    gemm_qkv<<<dim3(32,24,1), 256, 0, stream>>>(xb, wqb, wkb, wvb, qb, kb, vtb);

    retention<<<dim3(16,32,1), 256, 0, stream>>>(qb, kb, vtb, y0, y1);

    gn_stats<<<256, 256, 0, stream>>>(y0, y1, st);
    gn_norm<<<1024, 256, 0, stream>>>(y0, y1, st, gw, gb, ynb);

    gemm_out<<<dim3(32,16,1), 256, 0, stream>>>(ynb, wob, (float*)d_out);
}

// Round 7
// 185.150 us; speedup vs baseline: 1.0195x; 1.0195x over previous
//
#include <hip/hip_runtime.h>
#include <stdint.h>

// MultiScaleRetention pipeline, R7 = R6 gemm_qkv (kept) + retention reverted to
// R5 structure (64-j chunks, stride-64 rows, 8-chunk XOR swizzle, 32KB LDS).
// R6 post-mortem: j-128 retention regressed 35->53us (VGPR 128, 2.79M LDS
// conflicts from unswizzled c&8 chunk bit, 64KB LDS @ 2 blocks/CU). gemm_qkv
// R6 changes (mul-chain decay, single-pass epilogue) retained: ~42.6 -> <~30us.
//
// ws layout: [0,8) xb (reused as Y1 fp32 [bh][64d][1024t] after gemm_qkv)
// [8,10) wqb [10,12) wkb [12,14) wvb [14,16) wob
// [16,24) qb [B,H,T,DH] bf16  [24,32) kb same  [32,40) vtb [B,H,DH,T] bf16
// [40,56) Y0 fp32 [bh][64d][2048t]  [56,64) ynb bf16 [t][c]
// [64MB) st (128 floats)

#define SEQ 2048

typedef __bf16 bf16x8 __attribute__((ext_vector_type(8)));
typedef float  floatx4 __attribute__((ext_vector_type(4)));
typedef unsigned short ushort4v __attribute__((ext_vector_type(4)));

__device__ __forceinline__ unsigned short f2bf(float f){
    __bf16 h = (__bf16)f;
    return __builtin_bit_cast(unsigned short, h);
}

__device__ __forceinline__ void gload_lds16(const void* g, void* l){
    __builtin_amdgcn_global_load_lds(
        (const __attribute__((address_space(1))) unsigned int*)g,
        (__attribute__((address_space(3))) unsigned int*)l, 16, 0, 0);
}

// ---------------------------------------------------------------- fused cvt + st zero
__global__ __launch_bounds__(256)
void cvt_all(const float* __restrict__ x,
             const float* __restrict__ w0, const float* __restrict__ w1,
             const float* __restrict__ w2, const float* __restrict__ w3,
             unsigned short* __restrict__ xb,
             unsigned short* __restrict__ o0, unsigned short* __restrict__ o1,
             unsigned short* __restrict__ o2, unsigned short* __restrict__ o3,
             float* __restrict__ st){
    const int blk = blockIdx.x;
    if(blk == 0 && threadIdx.x < 128) st[threadIdx.x] = 0.0f;
    const float* src; unsigned short* dst; size_t i;
    if(blk < 4096){ src = x; dst = xb; i = (size_t)blk*256 + threadIdx.x; }
    else {
        const int seg = (blk - 4096) >> 10;
        src = seg==0?w0:seg==1?w1:seg==2?w2:w3;
        dst = seg==0?o0:seg==1?o1:seg==2?o2:o3;
        i = (size_t)((blk - 4096) & 1023)*256 + threadIdx.x;
    }
    float4 v = ((const float4*)src)[i];
    ushort4v o;
    o[0]=f2bf(v.x); o[1]=f2bf(v.y); o[2]=f2bf(v.z); o[3]=f2bf(v.w);
    *(ushort4v*)&dst[i*4] = o;
}

// ---------------------------------------------------------------- fused QKV GEMM
// grid (32,24): y<8 Q (scale 0.125*gamma^t), y<16 K (gamma^-t), else V^T.
// Epilogue: single-pass 128x128 LDS transpose (32KB), decay via mul chains.
__global__ __launch_bounds__(256, 3)
void gemm_qkv(const unsigned short* __restrict__ A,
              const unsigned short* __restrict__ Wq,
              const unsigned short* __restrict__ Wk,
              const unsigned short* __restrict__ Wv,
              unsigned short* __restrict__ Qo,
              unsigned short* __restrict__ Ko,
              unsigned short* __restrict__ Vo)
{
    __shared__ unsigned short smem[16384];  // main loop: As=[0,4096), Bs=[4096,8192); epi: 128x128
    unsigned short* As = smem;
    unsigned short* Bs = smem + 4096;
    const int tid  = threadIdx.x;
    const int w    = tid >> 6, lane = tid & 63, q = lane >> 4, cl = lane & 15;
    const int i0   = blockIdx.x * 128;
    const int ysel = blockIdx.y;
    int mode, n0;
    const unsigned short* Bw;
    unsigned short* O;
    if(ysel < 8)      { mode = 0; Bw = Wq; O = Qo; n0 = ysel*128; }
    else if(ysel < 16){ mode = 1; Bw = Wk; O = Ko; n0 = (ysel-8)*128; }
    else              { mode = 2; Bw = Wv; O = Vo; n0 = (ysel-16)*128; }
    const int wm = (w & 1) * 64, wn = (w >> 1) * 64;

    floatx4 acc[4][4];
    #pragma unroll
    for(int a=0;a<4;a++)
        #pragma unroll
        for(int b=0;b<4;b++) acc[a][b] = (floatx4)(0.0f);

    const int srow = lane >> 2;
    const int soff = (lane & 3) * 16;

    for(int k0 = 0; k0 < 1024; k0 += 32){
        __syncthreads();
        #pragma unroll
        for(int t=0;t<2;t++){
            const int ra = (w*2 + t) * 16;
            gload_lds16((const char*)A  + ((size_t)(i0 + ra + srow)*1024 + k0)*2 + soff,
                        (char*)&As[ra*32]);
            gload_lds16((const char*)Bw + ((size_t)(n0 + ra + srow)*1024 + k0)*2 + soff,
                        (char*)&Bs[ra*32]);
        }
        __syncthreads();

        bf16x8 af[4], bfr[4];
        #pragma unroll
        for(int mi=0;mi<4;mi++) af[mi]  = *(const bf16x8*)&As[(wm + mi*16 + cl)*32 + q*8];
        #pragma unroll
        for(int ni=0;ni<4;ni++) bfr[ni] = *(const bf16x8*)&Bs[(wn + ni*16 + cl)*32 + q*8];
        #pragma unroll
        for(int mi=0;mi<4;mi++)
            #pragma unroll
            for(int ni=0;ni<4;ni++)
                acc[mi][ni] = __builtin_amdgcn_mfma_f32_16x16x32_bf16(af[mi], bfr[ni], acc[mi][ni], 0, 0, 0);
    }

    const int b = i0 >> 11;
    const int tb = i0 & 2047;               // within-batch token base
    __syncthreads();                        // protect smem reuse vs last frag reads

    if(mode < 2){
        // decay chain constants: h constant per thread (wn fixed, ni*16 < 64)
        const int h = (n0 + wn) >> 6;
        const float gamma = 1.0f - __builtin_ldexpf(1.0f, -5 - h);
        const float lgh = log2f(gamma);
        float g1p, base;
        if(mode == 0){ g1p = gamma;        base = exp2f((float)tb * lgh) * 0.125f; }
        else         { g1p = 1.0f / gamma; base = exp2f(-(float)tb * lgh); }
        const float g2 = g1p*g1p, g4 = g2*g2, g8 = g4*g4, g16 = g8*g8;
        const float g32 = g16*g16, g64 = g32*g32;
        float sq = base;
        if(q & 1) sq *= g4;
        if(q & 2) sq *= g8;
        if(wm)    sq *= g64;

        // write [128 t][128 d] swizzled
        #pragma unroll
        for(int ni=0;ni<4;ni++){
            const int d = wn + ni*16 + cl, d8 = d >> 3, d7 = d & 7;
            float cur = sq;
            #pragma unroll
            for(int mi=0;mi<4;mi++){
                const int tr0 = wm + mi*16 + q*4;
                float v0 = cur, v1 = v0*g1p, v2 = v1*g1p, v3 = v2*g1p;
                smem[(tr0+0)*128 + ((d8 ^ ((tr0+0)&7))*8) + d7] = f2bf(acc[mi][ni][0]*v0);
                smem[(tr0+1)*128 + ((d8 ^ ((tr0+1)&7))*8) + d7] = f2bf(acc[mi][ni][1]*v1);
                smem[(tr0+2)*128 + ((d8 ^ ((tr0+2)&7))*8) + d7] = f2bf(acc[mi][ni][2]*v2);
                smem[(tr0+3)*128 + ((d8 ^ ((tr0+3)&7))*8) + d7] = f2bf(acc[mi][ni][3]*v3);
                cur *= g16;
            }
        }
        __syncthreads();
        // read + store: 2 rows/thread, 4-lane 64B runs
        const int part = tid & 3;
        #pragma unroll
        for(int rr=0;rr<2;rr++){
            const int row = (tid>>2)*2 + rr;
            const int tt = tb + row;
            #pragma unroll
            for(int k=0;k<4;k++){
                const int c = k*4 + part;
                bf16x8 vrow = *(const bf16x8*)&smem[row*128 + ((c ^ (row&7))*8)];
                const int h2 = (n0 + c*8) >> 6, dd = (c*8) & 63;
                *(bf16x8*)&O[(((size_t)(b*16 + h2))*2048 + tt)*64 + dd] = vrow;
            }
        }
    } else {
        // V^T: write [128 d][128 t] swizzled (b64 packed), read rows coalesced
        #pragma unroll
        for(int ni=0;ni<4;ni++){
            const int drow = wn + ni*16 + cl, dr7 = drow & 7;
            #pragma unroll
            for(int mi=0;mi<4;mi++){
                const int ch = (wm>>3) + mi*2 + (q>>1);     // t-chunk 0..15
                const int phys = (ch & 8) | ((ch & 7) ^ dr7);
                ushort4v pk;
                #pragma unroll
                for(int r=0;r<4;r++) pk[r] = f2bf(acc[mi][ni][r]);
                *(ushort4v*)&smem[drow*128 + phys*8 + (q&1)*4] = pk;
            }
        }
        __syncthreads();
        const int part = tid & 3;
        #pragma unroll
        for(int rr=0;rr<2;rr++){
            const int row = (tid>>2)*2 + rr;                // d-row 0..127
            const int dg = n0 + row;
            const int h2 = dg >> 6, dd = dg & 63;
            #pragma unroll
            for(int k=0;k<4;k++){
                const int c = k*4 + part;
                const int phys = (c & 8) | ((c & 7) ^ (row & 7));
                bf16x8 vrow = *(const bf16x8*)&smem[row*128 + phys*8];
                *(bf16x8*)&O[(((size_t)(b*16 + h2))*64 + dd)*2048 + tb + c*8] = vrow;
            }
        }
    }
}

// ---------------------------------------------------------------- retention core (R5 structure)
// S^T = K*Q^T (b64 Ss writes / b128 reads), Y^T = V^T*S^T, [bh][d][t] coalesced.
// grid (16,32): pair (x,15-x) split into two uniform 17-chunk (64-j) blocks.
__global__ __launch_bounds__(256, 2)
void retention(const unsigned short* __restrict__ Q,
               const unsigned short* __restrict__ K,
               const unsigned short* __restrict__ VT,
               float* __restrict__ Y0, float* __restrict__ Y1)
{
    __shared__ unsigned short Ks[64*64];
    __shared__ unsigned short Vs[64*64];
    __shared__ unsigned short Ss[4][32*64];

    const int tid = threadIdx.x;
    const int w = tid >> 6, lane = tid & 63, q = lane >> 4, cl = lane & 15;
    const int s = blockIdx.x >> 3, x = blockIdx.x & 7;
    const int bh = blockIdx.y;
    const int wm = w * 32;
    const int l3 = lane >> 3, l7 = lane & 7;
    const int c8 = l7 ^ l3;
    const int cl7 = cl & 7;

    int segbt[2], segjb[2], segje[2], nseg;
    if(s == 0){ nseg = 2;
        segbt[0] = x;     segjb[0] = 0;      segje[0] = 2*x + 2;
        segbt[1] = 15-x;  segjb[1] = 0;      segje[1] = 15 - 2*x;
    } else { nseg = 1;
        segbt[0] = 15-x;  segjb[0] = 15-2*x; segje[0] = 32 - 2*x;
    }

    for(int seg = 0; seg < nseg; seg++){
        const int bt = segbt[seg], jb = segjb[seg], je = segje[seg];
        const int i0 = bt * 128;

        bf16x8 qf[2][2];
        #pragma unroll
        for(int mi=0;mi<2;mi++)
            #pragma unroll
            for(int kk=0;kk<2;kk++)
                qf[mi][kk] = *(const bf16x8*)(Q + ((size_t)bh*SEQ + i0 + wm + mi*16 + cl)*64 + kk*32 + q*8);

        floatx4 Yacc[2][4];
        #pragma unroll
        for(int a=0;a<2;a++)
            #pragma unroll
            for(int b=0;b<4;b++) Yacc[a][b] = (floatx4)(0.0f);

        for(int jt = jb; jt < je; jt++){
            const int j0 = jt * 64;
            __syncthreads();
            #pragma unroll
            for(int t=0;t<2;t++){
                const int r = w*16 + t*8 + l3;
                gload_lds16((const char*)K  + (((size_t)bh*SEQ + j0 + r)*64 + c8*8)*2,
                            (char*)&Ks[(w*16 + t*8)*64]);
                gload_lds16((const char*)VT + (((size_t)bh*64 + r)*SEQ + j0 + c8*8)*2,
                            (char*)&Vs[(w*16 + t*8)*64]);
            }
            __syncthreads();

            // S^T[j][i] = K*Q^T : A-frag = K rows (m=j), B-frag = Q rows (n=i)
            floatx4 St[2][4];
            #pragma unroll
            for(int a=0;a<2;a++)
                #pragma unroll
                for(int b=0;b<4;b++) St[a][b] = (floatx4)(0.0f);
            #pragma unroll
            for(int kk=0;kk<2;kk++){
                #pragma unroll
                for(int ni=0;ni<4;ni++){
                    bf16x8 ak = *(const bf16x8*)&Ks[(ni*16 + cl)*64 + ((kk*4+q) ^ cl7)*8];
                    St[0][ni] = __builtin_amdgcn_mfma_f32_16x16x32_bf16(ak, qf[0][kk], St[0][ni], 0,0,0);
                    St[1][ni] = __builtin_amdgcn_mfma_f32_16x16x32_bf16(ak, qf[1][kk], St[1][ni], 0,0,0);
                }
            }

            // mask + pack; lane holds (i = wm+mi*16+cl, j = j0+ni*16+q*4+{0..3})
            const bool need_mask = (jt >= 2*bt);
            unsigned short* SsW = Ss[w];
            #pragma unroll
            for(int mi=0;mi<2;mi++){
                const int row = mi*16 + cl;
                const int sw = row & 7;
                const int ig = i0 + wm + row;
                #pragma unroll
                for(int ni=0;ni<4;ni++){
                    ushort4v pk;
                    #pragma unroll
                    for(int r=0;r<4;r++){
                        float v = St[mi][ni][r];
                        if(need_mask){
                            const int jg = j0 + ni*16 + q*4 + r;
                            if(ig < jg) v = 0.0f;
                        }
                        pk[r] = f2bf(v);
                    }
                    *(ushort4v*)&SsW[row*64 + (((ni*2 + (q>>1)) ^ sw)*8) + (q&1)*4] = pk;
                }
            }
            asm volatile("s_waitcnt lgkmcnt(0)" ::: "memory");  // per-wave region

            // Y^T += V^T * S^T : A-frag = V^T rows (m=d), B-frag = S^T (n=i)
            #pragma unroll
            for(int kk=0;kk<2;kk++){
                const int ch = ((kk*4+q) ^ cl7)*8;
                bf16x8 bs0 = *(const bf16x8*)&SsW[( 0 + cl)*64 + ch];
                bf16x8 bs1 = *(const bf16x8*)&SsW[(16 + cl)*64 + ch];
                #pragma unroll
                for(int nt=0;nt<4;nt++){
                    bf16x8 av = *(const bf16x8*)&Vs[(nt*16 + cl)*64 + ch];
                    Yacc[0][nt] = __builtin_amdgcn_mfma_f32_16x16x32_bf16(av, bs0, Yacc[0][nt], 0,0,0);
                    Yacc[1][nt] = __builtin_amdgcn_mfma_f32_16x16x32_bf16(av, bs1, Yacc[1][nt], 0,0,0);
                }
            }
        }

        // flush Y^T: (d = nt*16+q*4+r, i = i0+wm+mi*16+cl), coalesced in t
        #pragma unroll
        for(int mi=0;mi<2;mi++)
            #pragma unroll
            for(int nt=0;nt<4;nt++){
                const int ig = i0 + wm + mi*16 + cl;
                #pragma unroll
                for(int r=0;r<4;r++){
                    const int d = nt*16 + q*4 + r;
                    if(s == 0)
                        Y0[((size_t)bh*64 + d)*2048 + ig] = Yacc[mi][nt][r];
                    else
                        Y1[((size_t)bh*64 + d)*1024 + ig - 1024] = Yacc[mi][nt][r];
                }
            }
    }
}

// ---------------------------------------------------------------- GroupNorm stats
__global__ __launch_bounds__(256)
void gn_stats(const float* __restrict__ Y0, const float* __restrict__ Y1,
              float* __restrict__ st){
    const int g = blockIdx.x >> 3, s8 = blockIdx.x & 7;
    if(g >= 32) return;
    float s1 = 0.f, s2 = 0.f;
    #pragma unroll
    for(int it=0; it<16; it++){
        const int idx = it*256 + threadIdx.x;
        const int dl = idx >> 9;
        const int t4 = idx & 511;
        const int drow = g*64 + s8*8 + dl;
        float4 v = ((const float4*)Y0)[(size_t)drow*512 + t4];
        if(t4 >= 256){
            float4 u = ((const float4*)Y1)[(size_t)drow*256 + t4 - 256];
            v.x += u.x; v.y += u.y; v.z += u.z; v.w += u.w;
        }
        s1 += v.x + v.y + v.z + v.w;
        s2 += v.x*v.x + v.y*v.y + v.z*v.z + v.w*v.w;
    }
    #pragma unroll
    for(int o=32;o>0;o>>=1){ s1 += __shfl_down(s1,o); s2 += __shfl_down(s2,o); }
    __shared__ float r1[4], r2[4];
    const int w = threadIdx.x >> 6, lane = threadIdx.x & 63;
    if(lane == 0){ r1[w] = s1; r2[w] = s2; }
    __syncthreads();
    if(threadIdx.x == 0){
        atomicAdd(&st[g*2+0], r1[0]+r1[1]+r1[2]+r1[3]);
        atomicAdd(&st[g*2+1], r2[0]+r2[1]+r2[2]+r2[3]);
    }
}

// ---------------------------------------------------------------- GroupNorm apply + transpose
__global__ __launch_bounds__(256)
void gn_norm(const float* __restrict__ Y0, const float* __restrict__ Y1,
             const float* __restrict__ st,
             const float* __restrict__ gw, const float* __restrict__ gb,
             unsigned short* __restrict__ Out){
    __shared__ unsigned short T[64*72];
    const int g = blockIdx.x >> 5;
    if(g >= 32) return;
    const int t0 = (blockIdx.x & 31) * 64;
    const int h = g & 15, b = g >> 4;
    const float mean = st[g*2+0] * (1.0f/131072.0f);
    const float var  = st[g*2+1] * (1.0f/131072.0f) - mean*mean;
    const float inv  = rsqrtf(var + 1e-5f);
    const int tid = threadIdx.x;
    const bool hi = (t0 >= 1024);
    #pragma unroll
    for(int kk=0;kk<4;kk++){
        const int f4 = kk*256 + tid;
        const int d = f4 >> 4;
        const int t4l = f4 & 15;
        float4 v = ((const float4*)Y0)[(size_t)(g*64 + d)*512 + (t0>>2) + t4l];
        if(hi){
            float4 u = ((const float4*)Y1)[(size_t)(g*64 + d)*256 + ((t0-1024)>>2) + t4l];
            v.x += u.x; v.y += u.y; v.z += u.z; v.w += u.w;
        }
        const int c = h*64 + d;
        const float sc = inv * gw[c];
        const float bs = gb[c] - mean*sc;
        const int tl = t4l*4;
        T[(tl+0)*72 + d] = f2bf(v.x*sc + bs);
        T[(tl+1)*72 + d] = f2bf(v.y*sc + bs);
        T[(tl+2)*72 + d] = f2bf(v.z*sc + bs);
        T[(tl+3)*72 + d] = f2bf(v.w*sc + bs);
    }
    __syncthreads();
    #pragma unroll
    for(int it=0; it<2; it++){
        const int idx = it*256 + tid;
        const int tl = idx >> 3, segp = idx & 7;
        bf16x8 vrow = *(const bf16x8*)&T[tl*72 + segp*8];
        *(bf16x8*)&Out[((size_t)(b*2048 + t0 + tl))*1024 + h*64 + segp*8] = vrow;
    }
}

// ---------------------------------------------------------------- output GEMM
__global__ __launch_bounds__(256, 3)
void gemm_out(const unsigned short* __restrict__ A,
              const unsigned short* __restrict__ Bw,
              float* __restrict__ O)
{
    __shared__ unsigned short As[128*32];
    __shared__ unsigned short Bs[64*32];
    const int tid = threadIdx.x;
    const int w = tid >> 6, lane = tid & 63, q = lane >> 4, cl = lane & 15;
    const int i0 = blockIdx.x * 128, n0 = blockIdx.y * 64;
    const int wm = (w & 1) * 64, wn = (w >> 1) * 32;

    floatx4 acc[4][2];
    #pragma unroll
    for(int a=0;a<4;a++)
        #pragma unroll
        for(int b=0;b<2;b++) acc[a][b] = (floatx4)(0.0f);

    const int srow = lane >> 2;
    const int soff = (lane & 3) * 16;

    for(int k0 = 0; k0 < 1024; k0 += 32){
        __syncthreads();
        #pragma unroll
        for(int t=0;t<2;t++){
            const int ra = w*32 + t*16;
            gload_lds16((const char*)A + ((size_t)(i0 + ra + srow)*1024 + k0)*2 + soff,
                        (char*)&As[ra*32]);
        }
        gload_lds16((const char*)Bw + ((size_t)(n0 + w*16 + srow)*1024 + k0)*2 + soff,
                    (char*)&Bs[(w*16)*32]);
        __syncthreads();

        bf16x8 af[4], bfr[2];
        #pragma unroll
        for(int mi=0;mi<4;mi++) af[mi]  = *(const bf16x8*)&As[(wm + mi*16 + cl)*32 + q*8];
        #pragma unroll
        for(int ni=0;ni<2;ni++) bfr[ni] = *(const bf16x8*)&Bs[(wn + ni*16 + cl)*32 + q*8];
        #pragma unroll
        for(int mi=0;mi<4;mi++)
            #pragma unroll
            for(int ni=0;ni<2;ni++)
                acc[mi][ni] = __builtin_amdgcn_mfma_f32_16x16x32_bf16(af[mi], bfr[ni], acc[mi][ni], 0, 0, 0);
    }

    #pragma unroll
    for(int mi=0;mi<4;mi++)
        #pragma unroll
        for(int ni=0;ni<2;ni++){
            const int gi = i0 + wm + mi*16 + q*4;
            const int gn = n0 + wn + ni*16 + cl;
            #pragma unroll
            for(int r=0;r<4;r++) O[(size_t)(gi + r)*1024 + gn] = acc[mi][ni][r];
        }
}

// ---------------------------------------------------------------- launch
extern "C" void kernel_launch(void* const* d_in, const int* in_sizes, int n_in,
                              void* d_out, int out_size, void* d_ws, size_t ws_size,
                              hipStream_t stream){
    const float* x  = (const float*)d_in[0];
    const float* Wq = (const float*)d_in[1];
    const float* Wk = (const float*)d_in[2];
    const float* Wv = (const float*)d_in[3];
    const float* Wo = (const float*)d_in[4];
    const float* gw = (const float*)d_in[5];
    const float* gb = (const float*)d_in[6];

    char* ws = (char*)d_ws;
    unsigned short* xb  = (unsigned short*)(ws + ((size_t) 0<<20));
    unsigned short* wqb = (unsigned short*)(ws + ((size_t) 8<<20));
    unsigned short* wkb = (unsigned short*)(ws + ((size_t)10<<20));
    unsigned short* wvb = (unsigned short*)(ws + ((size_t)12<<20));
    unsigned short* wob = (unsigned short*)(ws + ((size_t)14<<20));
    unsigned short* qb  = (unsigned short*)(ws + ((size_t)16<<20));
    unsigned short* kb  = (unsigned short*)(ws + ((size_t)24<<20));
    unsigned short* vtb = (unsigned short*)(ws + ((size_t)32<<20));
    float*          y0  = (float*)         (ws + ((size_t)40<<20));
    unsigned short* ynb = (unsigned short*)(ws + ((size_t)56<<20));
    float*          y1  = (float*)         (ws + ((size_t) 0<<20));   // over xb
    float*          st  = (float*)         (ws + ((size_t)64<<20));   // 128 floats

    cvt_all<<<8192, 256, 0, stream>>>(x, Wq, Wk, Wv, Wo, xb, wqb, wkb, wvb, wob, st);

    gemm_qkv<<<dim3(32,24,1), 256, 0, stream>>>(xb, wqb, wkb, wvb, qb, kb, vtb);

    retention<<<dim3(16,32,1), 256, 0, stream>>>(qb, kb, vtb, y0, y1);

    gn_stats<<<256, 256, 0, stream>>>(y0, y1, st);
    gn_norm<<<1024, 256, 0, stream>>>(y0, y1, st, gw, gb, ynb);

    gemm_out<<<dim3(32,16,1), 256, 0, stream>>>(ynb, wob, (float*)d_out);
}